// Round 3
// baseline (157.363 us; speedup 1.0000x reference)
//
#include <hip/hip_runtime.h>
#include <math.h>

typedef _Float16 f16;
typedef _Float16 h4 __attribute__((ext_vector_type(4)));
typedef _Float16 h8 __attribute__((ext_vector_type(8)));
typedef float f32x4 __attribute__((ext_vector_type(4)));

#define QSCALE 0.17677669529663689f  // 1/sqrt(32)

// ---------------- Kernel A: projection GEMM (f16 MFMA) ----------------
// grid (512 row-tiles, 2 phases). phase0: q_x -> {q(scaled), g(sigmoid)};
// phase1: kv_x -> {k, v(transposed store)}. Block 256 thr = 4 waves (2x2),
// out tile 128x128 per weight. LDS: X 32KB + W 32KB, XOR-swizzled 16B chunks.
__global__ __launch_bounds__(256) void proj_mfma(
    const float* __restrict__ q_x, const float* __restrict__ kv_x,
    const float* __restrict__ wq, const float* __restrict__ wk,
    const float* __restrict__ wv, const float* __restrict__ wg,
    const float* __restrict__ bg,
    f16* __restrict__ qb, f16* __restrict__ kb,
    f16* __restrict__ vbT, f16* __restrict__ gb)
{
    __shared__ char lds[65536];
    char* xl = lds;
    char* wl = lds + 32768;
    const int t = threadIdx.x;
    const int lane = t & 63, wave = t >> 6;
    const int wr = wave >> 1, wc = wave & 1;
    const int lo = lane & 15, hi = lane >> 4;
    const int phase = blockIdx.y;
    const int row0 = blockIdx.x * 128;
    const float* xsrc = phase ? kv_x : q_x;

    // stage X tile 128x128 fp32 -> f16 swizzled LDS
    #pragma unroll
    for (int j = 0; j < 16; ++j) {
        int f = t + 256 * j;
        int row = f >> 5, c4 = f & 31;
        float4 v = *(const float4*)(xsrc + (size_t)(row0 + row) * 128 + c4 * 4);
        h4 hv = {(f16)v.x, (f16)v.y, (f16)v.z, (f16)v.w};
        *(h4*)(xl + row * 256 + (((c4 >> 1) ^ (row & 7)) << 4) + ((c4 & 1) << 3)) = hv;
    }

    for (int sub = 0; sub < 2; ++sub) {
        const int pid = phase * 2 + sub;
        const float* w = (pid == 0) ? wq : (pid == 1) ? wg : (pid == 2) ? wk : wv;
        __syncthreads();  // xl ready (sub0) / wl reads done (sub1)
        #pragma unroll
        for (int j = 0; j < 16; ++j) {
            int f = t + 256 * j;
            int row = f >> 5, c4 = f & 31;
            float4 v = *(const float4*)(w + (size_t)row * 128 + c4 * 4);
            h4 hv = {(f16)v.x, (f16)v.y, (f16)v.z, (f16)v.w};
            *(h4*)(wl + row * 256 + (((c4 >> 1) ^ (row & 7)) << 4) + ((c4 & 1) << 3)) = hv;
        }
        __syncthreads();

        f32x4 acc[4][4];
        #pragma unroll
        for (int m = 0; m < 4; ++m)
            #pragma unroll
            for (int n = 0; n < 4; ++n) acc[m][n] = (f32x4){0.f, 0.f, 0.f, 0.f};

        #pragma unroll
        for (int kk = 0; kk < 4; ++kk) {
            const int swz = ((hi + 4 * kk) ^ (lo & 7)) << 4;
            h8 af[4], bf[4];
            #pragma unroll
            for (int m = 0; m < 4; ++m)
                af[m] = *(const h8*)(xl + (lo + 16 * m + 64 * wr) * 256 + swz);
            #pragma unroll
            for (int n = 0; n < 4; ++n)
                bf[n] = *(const h8*)(wl + (lo + 16 * n + 64 * wc) * 256 + swz);
            #pragma unroll
            for (int m = 0; m < 4; ++m)
                #pragma unroll
                for (int n = 0; n < 4; ++n)
                    acc[m][n] = __builtin_amdgcn_mfma_f32_16x16x32_f16(af[m], bf[n], acc[m][n], 0, 0, 0);
        }

        // epilogue: D[row=(l>>4)*4+r][col=l&15]
        #pragma unroll
        for (int n = 0; n < 4; ++n) {
            const int col = 64 * wc + 16 * n + lo;
            const float bgv = (pid == 1) ? bg[col] : 0.f;
            #pragma unroll
            for (int m = 0; m < 4; ++m) {
                if (pid == 3) {
                    // V transposed: vbT[((s*4+h)*32+dh)*256 + key]
                    int rg = row0 + 64 * wr + 16 * m + 4 * hi;
                    int sidx = rg >> 8, key = rg & 255;
                    int hh = col >> 5, dh = col & 31;
                    h4 hv = {(f16)acc[m][n][0], (f16)acc[m][n][1],
                             (f16)acc[m][n][2], (f16)acc[m][n][3]};
                    *(h4*)(vbT + (((size_t)sidx * 4 + hh) * 32 + dh) * 256 + key) = hv;
                } else {
                    f16* dst = (pid == 0) ? qb : (pid == 1) ? gb : kb;
                    #pragma unroll
                    for (int r = 0; r < 4; ++r) {
                        int rg = row0 + 64 * wr + 16 * m + 4 * hi + r;
                        float v = acc[m][n][r];
                        if (pid == 0) v *= QSCALE;
                        else if (pid == 1) v = 1.f / (1.f + __expf(-(v + bgv)));
                        dst[(size_t)rg * 128 + col] = (f16)v;
                    }
                }
            }
        }
    }
}

// ---------------- Kernel B: attention (f16 MFMA, full-row softmax) ----------------
// grid (16 = h*4 + qblk, S=256), block 256 = 4 waves, each wave owns a 16-q strip.
// Full 256-key score row in registers (16 x f32x4); single softmax pass;
// P through per-wave XOR-swizzled LDS; V B-frags from transposed vbT.
__global__ __launch_bounds__(256) void attn_mfma(
    const f16* __restrict__ qb, const f16* __restrict__ kb,
    const f16* __restrict__ vbT, const f16* __restrict__ gb,
    const float* __restrict__ bias1, const float* __restrict__ bias2,
    f16* __restrict__ ob)
{
    __shared__ float b2s[256];
    __shared__ char plds[32768];  // 4 waves x 8KB (16 rows x 512B)
    const int x = blockIdx.x;
    const int h = x >> 2, qblk = x & 3;
    const int s = blockIdx.y;
    const int t = threadIdx.x, wave = t >> 6, lane = t & 63;
    const int lo = lane & 15, hi = lane >> 4;
    char* pw = plds + wave * 8192;
    const size_t rowbase = (size_t)s * 256;
    const int q0 = qblk * 64 + wave * 16;

    b2s[t] = bias2[s * 256 + t];
    __syncthreads();

    // Q A-frag: A[q=lo][d=8hi+j]
    h8 qf = *(const h8*)(qb + (rowbase + q0 + lo) * 128 + h * 32 + 8 * hi);

    // C-init with bias1 + bias2, then QK^T: 16 key-tiles of 16
    const float* b1 = bias1 + (size_t)h * 65536;
    f32x4 acc[16];
    #pragma unroll
    for (int nt = 0; nt < 16; ++nt) {
        float b2v = b2s[16 * nt + lo];
        #pragma unroll
        for (int r = 0; r < 4; ++r)
            acc[nt][r] = b1[(q0 + 4 * hi + r) * 256 + 16 * nt + lo] + b2v;
    }
    #pragma unroll
    for (int nt = 0; nt < 16; ++nt) {
        // K B-frag: B[d=8hi+j][key=lo]
        h8 kf = *(const h8*)(kb + (rowbase + 16 * nt + lo) * 128 + h * 32 + 8 * hi);
        acc[nt] = __builtin_amdgcn_mfma_f32_16x16x32_f16(qf, kf, acc[nt], 0, 0, 0);
    }

    // single-pass softmax per row (row = 4hi+r, cols = 16nt+lo)
    float inv_l[4];
    #pragma unroll
    for (int r = 0; r < 4; ++r) {
        float mx = acc[0][r];
        #pragma unroll
        for (int nt = 1; nt < 16; ++nt) mx = fmaxf(mx, acc[nt][r]);
        #pragma unroll
        for (int w = 1; w < 16; w <<= 1) mx = fmaxf(mx, __shfl_xor(mx, w, 16));
        float sm = 0.f;
        #pragma unroll
        for (int nt = 0; nt < 16; ++nt) {
            float p = __expf(acc[nt][r] - mx);
            acc[nt][r] = p;
            sm += p;
        }
        #pragma unroll
        for (int w = 1; w < 16; w <<= 1) sm += __shfl_xor(sm, w, 16);
        inv_l[r] = 1.f / sm;
    }

    // P -> LDS (f16, unnormalized), XOR-swizzled 16B chunks
    #pragma unroll
    for (int nt = 0; nt < 16; ++nt)
        #pragma unroll
        for (int r = 0; r < 4; ++r) {
            int row = 4 * hi + r, k = 16 * nt + lo;
            int cs = (k >> 3) ^ (row & 7);
            *(f16*)(pw + row * 512 + cs * 16 + (k & 7) * 2) = (f16)acc[nt][r];
        }

    // PV: A = P[q=lo][k=32kt+8hi+j] (swizzled ds_read_b128), B = V from vbT
    const f16* vbase = vbT + ((size_t)s * 4 + h) * 32 * 256;
    f32x4 Oa[2];
    Oa[0] = (f32x4){0.f, 0.f, 0.f, 0.f};
    Oa[1] = (f32x4){0.f, 0.f, 0.f, 0.f};
    #pragma unroll
    for (int kt = 0; kt < 8; ++kt) {
        int cs = (4 * kt + hi) ^ (lo & 7);
        h8 pa = *(const h8*)(pw + lo * 512 + cs * 16);
        #pragma unroll
        for (int n2 = 0; n2 < 2; ++n2) {
            h8 vf = *(const h8*)(vbase + (size_t)(n2 * 16 + lo) * 256 + 32 * kt + 8 * hi);
            Oa[n2] = __builtin_amdgcn_mfma_f32_16x16x32_f16(pa, vf, Oa[n2], 0, 0, 0);
        }
    }

    // epilogue: normalize, gate, store f16. D[row=4hi+r][col=lo]
    #pragma unroll
    for (int n2 = 0; n2 < 2; ++n2)
        #pragma unroll
        for (int r = 0; r < 4; ++r) {
            size_t idx = (rowbase + q0 + 4 * hi + r) * 128 + h * 32 + n2 * 16 + lo;
            float g = (float)gb[idx];
            ob[idx] = (f16)(Oa[n2][r] * inv_l[r] * g);
        }
}

// ---------------- Kernel C: output GEMM (f16 MFMA, fp32 out + bo) ----------------
__global__ __launch_bounds__(256) void out_mfma(
    const f16* __restrict__ ob, const float* __restrict__ wo,
    const float* __restrict__ bo, float* __restrict__ out)
{
    __shared__ char lds[65536];
    char* xl = lds;
    char* wl = lds + 32768;
    const int t = threadIdx.x;
    const int lane = t & 63, wave = t >> 6;
    const int wr = wave >> 1, wc = wave & 1;
    const int lo = lane & 15, hi = lane >> 4;
    const int row0 = blockIdx.x * 128;

    // stage ob tile (already f16): 16B chunks, swizzled
    #pragma unroll
    for (int j = 0; j < 8; ++j) {
        int f = t + 256 * j;
        int row = f >> 4, c8 = f & 15;
        h8 v = *(const h8*)(ob + (size_t)(row0 + row) * 128 + c8 * 8);
        *(h8*)(xl + row * 256 + ((c8 ^ (row & 7)) << 4)) = v;
    }
    // stage wo fp32 -> f16
    #pragma unroll
    for (int j = 0; j < 16; ++j) {
        int f = t + 256 * j;
        int row = f >> 5, c4 = f & 31;
        float4 v = *(const float4*)(wo + (size_t)row * 128 + c4 * 4);
        h4 hv = {(f16)v.x, (f16)v.y, (f16)v.z, (f16)v.w};
        *(h4*)(wl + row * 256 + (((c4 >> 1) ^ (row & 7)) << 4) + ((c4 & 1) << 3)) = hv;
    }
    __syncthreads();

    f32x4 acc[4][4];
    #pragma unroll
    for (int m = 0; m < 4; ++m)
        #pragma unroll
        for (int n = 0; n < 4; ++n) acc[m][n] = (f32x4){0.f, 0.f, 0.f, 0.f};

    #pragma unroll
    for (int kk = 0; kk < 4; ++kk) {
        const int swz = ((hi + 4 * kk) ^ (lo & 7)) << 4;
        h8 af[4], bf[4];
        #pragma unroll
        for (int m = 0; m < 4; ++m)
            af[m] = *(const h8*)(xl + (lo + 16 * m + 64 * wr) * 256 + swz);
        #pragma unroll
        for (int n = 0; n < 4; ++n)
            bf[n] = *(const h8*)(wl + (lo + 16 * n + 64 * wc) * 256 + swz);
        #pragma unroll
        for (int m = 0; m < 4; ++m)
            #pragma unroll
            for (int n = 0; n < 4; ++n)
                acc[m][n] = __builtin_amdgcn_mfma_f32_16x16x32_f16(af[m], bf[n], acc[m][n], 0, 0, 0);
    }

    #pragma unroll
    for (int n = 0; n < 4; ++n) {
        const int col = 64 * wc + 16 * n + lo;
        const float bov = bo[col];
        #pragma unroll
        for (int m = 0; m < 4; ++m)
            #pragma unroll
            for (int r = 0; r < 4; ++r)
                out[(size_t)(row0 + 64 * wr + 16 * m + 4 * hi + r) * 128 + col] = acc[m][n][r] + bov;
    }
}

extern "C" void kernel_launch(void* const* d_in, const int* in_sizes, int n_in,
                              void* d_out, int out_size, void* d_ws, size_t ws_size,
                              hipStream_t stream)
{
    const float* q_x   = (const float*)d_in[0];
    const float* kv_x  = (const float*)d_in[1];
    const float* bias1 = (const float*)d_in[2];
    const float* bias2 = (const float*)d_in[3];
    const float* wq    = (const float*)d_in[4];
    const float* wk    = (const float*)d_in[5];
    const float* wv    = (const float*)d_in[6];
    const float* wg    = (const float*)d_in[7];
    const float* bg    = (const float*)d_in[8];
    const float* wo    = (const float*)d_in[9];
    const float* bo    = (const float*)d_in[10];
    float* out = (float*)d_out;

    const size_t RC = (size_t)65536 * 128;
    f16* ws  = (f16*)d_ws;
    f16* qb  = ws;
    f16* kb  = ws + RC;
    f16* vbT = ws + 2 * RC;
    f16* gb  = ws + 3 * RC;
    f16* ob  = ws + 4 * RC;

    proj_mfma<<<dim3(512, 2), 256, 0, stream>>>(q_x, kv_x, wq, wk, wv, wg, bg, qb, kb, vbT, gb);
    attn_mfma<<<dim3(16, 256), 256, 0, stream>>>(qb, kb, vbT, gb, bias1, bias2, ob);
    out_mfma<<<512, 256, 0, stream>>>(ob, wo, bo, out);
}